// Round 2
// baseline (653.125 us; speedup 1.0000x reference)
//
#include <hip/hip_runtime.h>
#include <stdint.h>

#define N_NODES 200000
#define N_EDGES 600000
#define SCAN_CHUNK 1024
#define SCAN_BLOCKS ((N_NODES + SCAN_CHUNK - 1) / SCAN_CHUNK)  // 196
#define GRID_AGG 4096
#define NWAVES (GRID_AGG * 4)  // 16384 waves, ~36.6 edges each

typedef __attribute__((ext_vector_type(8))) short short8;
typedef __attribute__((ext_vector_type(4))) float floatx4;

static __device__ __forceinline__ unsigned short f2bf(float f) {
  union { float f; unsigned u; } c; c.f = f;
  unsigned u = c.u;
  unsigned r = (u + 0x7fffu + ((u >> 16) & 1u)) >> 16;
  return (unsigned short)r;
}
static __device__ __forceinline__ float asf(unsigned u) {
  union { unsigned u; float f; } c; c.u = u; return c.f;
}

// ---------------- weight prep: f32 [128][128] -> bf16 transposed [n][k] ----------------
__global__ __launch_bounds__(256) void prep_kernel(
    const float* w0, const float* w1, const float* w2, const float* w3, const float* w4,
    unsigned short* out) {
  const float* src;
  switch (blockIdx.y) {
    case 0: src = w0; break;
    case 1: src = w1; break;
    case 2: src = w2; break;
    case 3: src = w3; break;
    default: src = w4; break;
  }
  unsigned short* dst = out + (size_t)blockIdx.y * 16384;
  int t = blockIdx.x * 256 + threadIdx.x;  // 0..4095
#pragma unroll
  for (int i = 0; i < 4; ++i) {
    int idx = t + 4096 * i;  // idx = n*128 + k
    int n = idx >> 7, k = idx & 127;
    dst[idx] = f2bf(src[k * 128 + n]);
  }
}

// ---------------- CSR build ----------------
__global__ __launch_bounds__(256) void hist_kernel(const int* __restrict__ dst, int* deg, int E) {
  int e = blockIdx.x * 256 + threadIdx.x;
  if (e < E) atomicAdd(&deg[dst[e]], 1);
}

// pass 1: per-block partial sums of deg
__global__ __launch_bounds__(256) void scan_sum_kernel(const int* __restrict__ deg, int* partial,
                                                       int n) {
  __shared__ int wsum[4];
  const int tid = threadIdx.x, lane = tid & 63, wid = tid >> 6;
  int idx0 = blockIdx.x * SCAN_CHUNK + tid * 4;
  int s = 0;
#pragma unroll
  for (int j = 0; j < 4; ++j) {
    int ix = idx0 + j;
    if (ix < n) s += deg[ix];
  }
#pragma unroll
  for (int d = 32; d >= 1; d >>= 1) s += __shfl_down(s, d, 64);
  if (lane == 0) wsum[wid] = s;
  __syncthreads();
  if (tid == 0) partial[blockIdx.x] = wsum[0] + wsum[1] + wsum[2] + wsum[3];
}

// pass 2: single-block exclusive scan of partials (nb <= 256), writes off[n]=total
__global__ __launch_bounds__(256) void scan_partials_kernel(int* partial, int* off, int nb, int n) {
  __shared__ int wsum[4];
  const int tid = threadIdx.x, lane = tid & 63, wid = tid >> 6;
  int val = (tid < nb) ? partial[tid] : 0;
  int incl = val;
#pragma unroll
  for (int d = 1; d < 64; d <<= 1) {
    int t = __shfl_up(incl, d, 64);
    if (lane >= d) incl += t;
  }
  if (lane == 63) wsum[wid] = incl;
  __syncthreads();
  int base = 0;
  for (int w = 0; w < wid; ++w) base += wsum[w];
  int excl = base + incl - val;
  if (tid < nb) partial[tid] = excl;
  if (tid == 0) off[n] = wsum[0] + wsum[1] + wsum[2] + wsum[3];
}

// pass 3: per-block local exclusive scan + block base; writes off[] and cursor[]
__global__ __launch_bounds__(256) void scan_apply_kernel(const int* __restrict__ partial, int* off,
                                                         int* cursor, int n) {
  __shared__ int wsum[4];
  const int tid = threadIdx.x, lane = tid & 63, wid = tid >> 6;
  int idx0 = blockIdx.x * SCAN_CHUNK + tid * 4;
  int v[4];
  int s = 0;
#pragma unroll
  for (int j = 0; j < 4; ++j) {
    int ix = idx0 + j;
    v[j] = (ix < n) ? off[ix] : 0;
    s += v[j];
  }
  int incl = s;
#pragma unroll
  for (int d = 1; d < 64; d <<= 1) {
    int t = __shfl_up(incl, d, 64);
    if (lane >= d) incl += t;
  }
  if (lane == 63) wsum[wid] = incl;
  __syncthreads();
  int base = partial[blockIdx.x];
  for (int w = 0; w < wid; ++w) base += wsum[w];
  int running = base + incl - s;
#pragma unroll
  for (int j = 0; j < 4; ++j) {
    int ix = idx0 + j;
    if (ix < n) { off[ix] = running; cursor[ix] = running; }
    running += v[j];
  }
}

// scatter src node ids AND edge_attr rows into CSR (dst-sorted) order
__global__ __launch_bounds__(256) void scatter_kernel(const int* __restrict__ dst,
                                                      const int* __restrict__ src,
                                                      const float* __restrict__ eattr, int* cursor,
                                                      int* srcs, float* eaC, int E) {
  int e = blockIdx.x * 256 + threadIdx.x;
  if (e < E) {
    int p = atomicAdd(&cursor[dst[e]], 1);
    srcs[p] = src[e];
    const float4* q = (const float4*)(eattr + (size_t)e * 16);
    float4* o = (float4*)(eaC + (size_t)p * 16);
    o[0] = q[0]; o[1] = q[1]; o[2] = q[2]; o[3] = q[3];
  }
}

// wave w handles nodes [waveStart[w], waveStart[w+1]): balanced-by-edges contiguous ranges
__global__ __launch_bounds__(256) void partition_kernel(const int* __restrict__ off,
                                                        int* waveStart) {
  int w = blockIdx.x * 256 + threadIdx.x;
  if (w > NWAVES) return;
  if (w == NWAVES) { waveStart[w] = N_NODES; return; }
  long long t = (long long)w * N_EDGES / NWAVES;
  int lo = 0, hi = N_NODES;
  while (lo < hi) {
    int mid = (lo + hi) >> 1;
    if (off[mid] < (int)t) lo = mid + 1; else hi = mid;
  }
  waveStart[w] = lo;
}

// ---------------- aggregation + z = (1+eps)*h + sum relu(h[src]+ef) ----------------
// one wave per balanced node-range; lane covers channels (2*lane, 2*lane+1).
// v3: (a) weight block held as 32 SCALAR floats pinned with scalar "+v" asm ties
//     (v2 used 64-bit vector asm operands -- suspected build failure; scalar float
//     "+v" is the known-good keep-alive idiom). Without the pin the compiler
//     rematerializes the 16 weight loads per edge (observed VGPR_Count=32).
//     (b) flat edge pipeline: gather batches of 8 cross node boundaries (mean
//     degree is 3, so per-node batching capped MLP at ~3); node flush happens
//     inline via wave-uniform scalar branches.
__global__ __launch_bounds__(256) void agg_z_kernel(
    const unsigned short* __restrict__ hB, const int* __restrict__ off,
    const int* __restrict__ waveStart, const int* __restrict__ srcs,
    const float* __restrict__ eaC,
    const float* __restrict__ We, const float* __restrict__ be,
    const float* __restrict__ epsPtr, unsigned short* __restrict__ z) {
  const int lane = threadIdx.x & 63;
  const int wv = threadIdx.x >> 6;
  const int c = lane * 2;
  // wx[d] = We[d][c], wy[d] = We[d][c+1]
  float wx[16], wy[16];
#pragma unroll
  for (int d = 0; d < 16; ++d) {
    float2 t = *((const float2*)(We + d * 128 + c));
    wx[d] = t.x; wy[d] = t.y;
  }
  // Pin the 32 weight scalars in VGPRs (prevent remat of the loads in the loop).
#pragma unroll
  for (int d = 0; d < 16; ++d) {
    asm volatile("" : "+v"(wx[d]));
    asm volatile("" : "+v"(wy[d]));
  }
  const float2 bev = *((const float2*)(be + c));
  const float epsp = 1.0f + epsPtr[0];
  const int w = blockIdx.x * 4 + wv;
  const int n0 = waveStart[w];
  const int n1 = waveStart[w + 1];
  if (n0 >= n1) return;

  // node-boundary window: offv[lane] = off[obase+lane]
  int obase = n0;
  int ox = obase + lane; if (ox > N_NODES) ox = N_NODES;
  int offv = off[ox];
  int n = n0;
  int e = __builtin_amdgcn_readlane(offv, 0);   // off[n0]
  int eE = __builtin_amdgcn_readlane(offv, 1);  // off[n0+1]
  const int eTot = off[n1];
  unsigned hwn = *((const unsigned*)(hB + (size_t)n * 128 + c));

  // src-id window: sbuf[lane] = srcs[ebase+lane]
  int ebase = e;
  int sx = ebase + lane; if (sx > N_EDGES - 1) sx = N_EDGES - 1;
  int sbuf = srcs[sx];

  float accx = 0.0f, accy = 0.0f;

#define FLUSH() do { \
    const float hx = asf(hwn << 16); \
    const float hy = asf(hwn & 0xffff0000u); \
    unsigned p = (unsigned)f2bf(fmaf(epsp, hx, accx)) | \
                 ((unsigned)f2bf(fmaf(epsp, hy, accy)) << 16); \
    *((unsigned*)(z + (size_t)n * 128 + c)) = p; \
    accx = 0.0f; accy = 0.0f; \
    ++n; \
  } while (0)

#define EDGE_COMPUTE(EIDX, HW) { \
    const float* ea = eaC + (size_t)(EIDX) * 16; \
    const float4 q0 = *((const float4*)(ea)); \
    const float4 q1 = *((const float4*)(ea + 4)); \
    const float4 q2 = *((const float4*)(ea + 8)); \
    const float4 q3 = *((const float4*)(ea + 12)); \
    float ax = bev.x, bx = 0.0f, ay = bev.y, by = 0.0f; \
    ax = fmaf(q0.x, wx[0], ax); ay = fmaf(q0.x, wy[0], ay); \
    bx = fmaf(q0.y, wx[1], bx); by = fmaf(q0.y, wy[1], by); \
    ax = fmaf(q0.z, wx[2], ax); ay = fmaf(q0.z, wy[2], ay); \
    bx = fmaf(q0.w, wx[3], bx); by = fmaf(q0.w, wy[3], by); \
    ax = fmaf(q1.x, wx[4], ax); ay = fmaf(q1.x, wy[4], ay); \
    bx = fmaf(q1.y, wx[5], bx); by = fmaf(q1.y, wy[5], by); \
    ax = fmaf(q1.z, wx[6], ax); ay = fmaf(q1.z, wy[6], ay); \
    bx = fmaf(q1.w, wx[7], bx); by = fmaf(q1.w, wy[7], by); \
    ax = fmaf(q2.x, wx[8], ax); ay = fmaf(q2.x, wy[8], ay); \
    bx = fmaf(q2.y, wx[9], bx); by = fmaf(q2.y, wy[9], by); \
    ax = fmaf(q2.z, wx[10], ax); ay = fmaf(q2.z, wy[10], ay); \
    bx = fmaf(q2.w, wx[11], bx); by = fmaf(q2.w, wy[11], by); \
    ax = fmaf(q3.x, wx[12], ax); ay = fmaf(q3.x, wy[12], ay); \
    bx = fmaf(q3.y, wx[13], bx); by = fmaf(q3.y, wy[13], by); \
    ax = fmaf(q3.z, wx[14], ax); ay = fmaf(q3.z, wy[14], ay); \
    bx = fmaf(q3.w, wx[15], bx); by = fmaf(q3.w, wy[15], by); \
    float mx = (ax + bx) + asf((HW) << 16); \
    float my = (ay + by) + asf((HW) & 0xffff0000u); \
    accx += fmaxf(mx, 0.0f); \
    accy += fmaxf(my, 0.0f); }

  while (e < eTot) {
    int m = eTot - e; if (m > 8) m = 8;
    if (e + m > ebase + 64) {
      ebase = e;
      int s2 = ebase + lane; if (s2 > N_EDGES - 1) s2 = N_EDGES - 1;
      sbuf = srcs[s2];
    }
    const int j = e - ebase;
    // issue up to 8 gathers (crossing node boundaries) before any compute
    unsigned hw[8];
#pragma unroll
    for (int k = 0; k < 8; ++k) {
      if (k < m) {
        const int sn = __builtin_amdgcn_readlane(sbuf, j + k);
        hw[k] = *((const unsigned*)(hB + (size_t)sn * 128 + c));
      }
    }
#pragma unroll
    for (int k = 0; k < 8; ++k) {
      if (k >= m) break;
      while (e == eE) {  // wave-uniform: flush finished node(s), enter next
        FLUSH();
        if (n + 1 - obase >= 64) {
          obase = n;
          int ox2 = obase + lane; if (ox2 > N_NODES) ox2 = N_NODES;
          offv = off[ox2];
        }
        eE = __builtin_amdgcn_readlane(offv, n + 1 - obase);
        hwn = *((const unsigned*)(hB + (size_t)n * 128 + c));
      }
      EDGE_COMPUTE(e, hw[k]);
      ++e;
    }
  }
  // flush last accumulated node + trailing empty nodes
  while (n < n1) {
    FLUSH();
    if (n < n1) hwn = *((const unsigned*)(hB + (size_t)n * 128 + c));
  }
#undef EDGE_COMPUTE
#undef FLUSH
}

// ---------------- fused (1 or 2)-layer MLP GEMM, M-tile=64, N=K=128, bf16 MFMA ----------------
__global__ __launch_bounds__(256) void mlp_kernel(
    const void* __restrict__ Ain, int aIsBf16,
    const unsigned short* __restrict__ W1t, const float* __restrict__ b1,
    const unsigned short* __restrict__ W2t, const float* __restrict__ b2,
    int twoStage, int outBf16, void* __restrict__ out) {
  __shared__ unsigned short sA[64][136];
  __shared__ unsigned short sW[128][136];
  const int tid = threadIdx.x;
  const int lane = tid & 63;
  const int wv = tid >> 6;
  const int lr = lane & 15, quad = lane >> 4;
  const int mw = wv >> 1, nw = wv & 1;
  const size_t rowBase = (size_t)blockIdx.x * 64;

  if (aIsBf16) {
    const uint4* src = (const uint4*)((const unsigned short*)Ain + rowBase * 128);
#pragma unroll
    for (int i = 0; i < 4; ++i) {
      int idx = tid + 256 * i;  // 0..1023 chunks of 8 bf16
      int r = idx >> 4, c8 = idx & 15;
      uint4 v = src[idx];
      *((uint4*)&sA[r][c8 * 8]) = v;
    }
  } else {
    const float4* src = (const float4*)((const float*)Ain + rowBase * 128);
#pragma unroll
    for (int i = 0; i < 8; ++i) {
      int idx = tid + 256 * i;  // 0..2047 float4
      int r = idx >> 5, c4 = idx & 31;
      float4 v = src[idx];
      uint2 p;
      p.x = (unsigned)f2bf(v.x) | ((unsigned)f2bf(v.y) << 16);
      p.y = (unsigned)f2bf(v.z) | ((unsigned)f2bf(v.w) << 16);
      *((uint2*)&sA[r][c4 * 4]) = p;
    }
  }
  {
    const uint4* srcw = (const uint4*)W1t;
#pragma unroll
    for (int i = 0; i < 8; ++i) {
      int idx = tid + 256 * i;  // 0..2047 chunks of 8 bf16
      int r = idx >> 4, c8 = idx & 15;
      *((uint4*)&sW[r][c8 * 8]) = srcw[idx];
    }
  }
  __syncthreads();

  floatx4 acc[2][4];
#pragma unroll
  for (int mi = 0; mi < 2; ++mi)
#pragma unroll
    for (int ni = 0; ni < 4; ++ni)
#pragma unroll
      for (int i = 0; i < 4; ++i) acc[mi][ni][i] = 0.0f;

#pragma unroll
  for (int kk = 0; kk < 4; ++kk) {
    short8 a[2], b[4];
#pragma unroll
    for (int mi = 0; mi < 2; ++mi)
      a[mi] = *((const short8*)&sA[32 * mw + 16 * mi + lr][kk * 32 + quad * 8]);
#pragma unroll
    for (int ni = 0; ni < 4; ++ni)
      b[ni] = *((const short8*)&sW[64 * nw + 16 * ni + lr][kk * 32 + quad * 8]);
#pragma unroll
    for (int mi = 0; mi < 2; ++mi)
#pragma unroll
      for (int ni = 0; ni < 4; ++ni)
        acc[mi][ni] = __builtin_amdgcn_mfma_f32_16x16x32_bf16(a[mi], b[ni], acc[mi][ni], 0, 0, 0);
  }

  if (!twoStage) {
#pragma unroll
    for (int mi = 0; mi < 2; ++mi)
#pragma unroll
      for (int ni = 0; ni < 4; ++ni)
#pragma unroll
        for (int i = 0; i < 4; ++i) {
          int row = 32 * mw + 16 * mi + quad * 4 + i;
          int col = 64 * nw + 16 * ni + lr;
          float v = fmaxf(acc[mi][ni][i] + b1[col], 0.0f);
          if (outBf16)
            ((unsigned short*)out)[(rowBase + row) * 128 + col] = f2bf(v);
          else
            ((float*)out)[(rowBase + row) * 128 + col] = v;
        }
    return;
  }

  __syncthreads();  // all stage-1 LDS reads done
  // write t = relu(z@W1+b1) into sA as bf16
#pragma unroll
  for (int mi = 0; mi < 2; ++mi)
#pragma unroll
    for (int ni = 0; ni < 4; ++ni)
#pragma unroll
      for (int i = 0; i < 4; ++i) {
        int row = 32 * mw + 16 * mi + quad * 4 + i;
        int col = 64 * nw + 16 * ni + lr;
        sA[row][col] = f2bf(fmaxf(acc[mi][ni][i] + b1[col], 0.0f));
      }
  // reload W2t
  {
    const uint4* srcw = (const uint4*)W2t;
#pragma unroll
    for (int i = 0; i < 8; ++i) {
      int idx = tid + 256 * i;
      int r = idx >> 4, c8 = idx & 15;
      *((uint4*)&sW[r][c8 * 8]) = srcw[idx];
    }
  }
  __syncthreads();

  floatx4 acc2[2][4];
#pragma unroll
  for (int mi = 0; mi < 2; ++mi)
#pragma unroll
    for (int ni = 0; ni < 4; ++ni)
#pragma unroll
      for (int i = 0; i < 4; ++i) acc2[mi][ni][i] = 0.0f;

#pragma unroll
  for (int kk = 0; kk < 4; ++kk) {
    short8 a[2], b[4];
#pragma unroll
    for (int mi = 0; mi < 2; ++mi)
      a[mi] = *((const short8*)&sA[32 * mw + 16 * mi + lr][kk * 32 + quad * 8]);
#pragma unroll
    for (int ni = 0; ni < 4; ++ni)
      b[ni] = *((const short8*)&sW[64 * nw + 16 * ni + lr][kk * 32 + quad * 8]);
#pragma unroll
    for (int mi = 0; mi < 2; ++mi)
#pragma unroll
      for (int ni = 0; ni < 4; ++ni)
        acc2[mi][ni] = __builtin_amdgcn_mfma_f32_16x16x32_bf16(a[mi], b[ni], acc2[mi][ni], 0, 0, 0);
  }

#pragma unroll
  for (int mi = 0; mi < 2; ++mi)
#pragma unroll
    for (int ni = 0; ni < 4; ++ni)
#pragma unroll
      for (int i = 0; i < 4; ++i) {
        int row = 32 * mw + 16 * mi + quad * 4 + i;
        int col = 64 * nw + 16 * ni + lr;
        float v = fmaxf(acc2[mi][ni][i] + b2[col], 0.0f);
        if (outBf16)
          ((unsigned short*)out)[(rowBase + row) * 128 + col] = f2bf(v);
        else
          ((float*)out)[(rowBase + row) * 128 + col] = v;
      }
}

extern "C" void kernel_launch(void* const* d_in, const int* in_sizes, int n_in,
                              void* d_out, int out_size, void* d_ws, size_t ws_size,
                              hipStream_t stream) {
  (void)in_sizes; (void)n_in; (void)out_size; (void)ws_size;
  const float* x = (const float*)d_in[0];
  const int* eidx = (const int*)d_in[1];
  const int* esrc = eidx;
  const int* edst = eidx + N_EDGES;
  const float* eattr = (const float*)d_in[2];
  const float* W_enc = (const float*)d_in[3];
  const float* b_enc = (const float*)d_in[4];
  const float* We1 = (const float*)d_in[5];
  const float* be1 = (const float*)d_in[6];
  const float* W11 = (const float*)d_in[7];
  const float* b11 = (const float*)d_in[8];
  const float* W12 = (const float*)d_in[9];
  const float* b12 = (const float*)d_in[10];
  const float* eps1 = (const float*)d_in[11];
  const float* We2 = (const float*)d_in[12];
  const float* be2 = (const float*)d_in[13];
  const float* W21 = (const float*)d_in[14];
  const float* b21 = (const float*)d_in[15];
  const float* W22 = (const float*)d_in[16];
  const float* b22 = (const float*)d_in[17];
  const float* eps2 = (const float*)d_in[18];

  char* ws = (char*)d_ws;
  size_t o = 0;
  unsigned short* wt = (unsigned short*)(ws + o); o += 163840;
  unsigned short* hB = (unsigned short*)(ws + o); o += 51200000ull;
  unsigned short* bufZ = (unsigned short*)(ws + o); o += 51200000ull;
  float* eaC = (float*)(ws + o); o += 38400000ull;
  int* off = (int*)(ws + o); o += ((N_NODES + 1) * 4 + 15) / 16 * 16;
  int* cursor = (int*)(ws + o); o += ((size_t)N_NODES * 4 + 15) / 16 * 16;
  int* srcs = (int*)(ws + o); o += (size_t)N_EDGES * 4;
  int* partial = (int*)(ws + o); o += (SCAN_BLOCKS * 4 + 15) / 16 * 16;
  int* waveStart = (int*)(ws + o); o += (size_t)(NWAVES + 1) * 4;

  unsigned short* Wt_enc = wt;
  unsigned short* Wt11 = wt + 16384;
  unsigned short* Wt12 = wt + 2 * 16384;
  unsigned short* Wt21 = wt + 3 * 16384;
  unsigned short* Wt22 = wt + 4 * 16384;

  hipMemsetAsync(off, 0, (N_NODES + 1) * sizeof(int), stream);
  prep_kernel<<<dim3(16, 5), 256, 0, stream>>>(W_enc, W11, W12, W21, W22, wt);

  // h0 = relu(x @ W_enc + b_enc) -> bf16
  mlp_kernel<<<3125, 256, 0, stream>>>(x, 0, Wt_enc, b_enc, Wt_enc, b_enc, 0, 1, hB);

  hist_kernel<<<(N_EDGES + 255) / 256, 256, 0, stream>>>(edst, off, N_EDGES);
  scan_sum_kernel<<<SCAN_BLOCKS, 256, 0, stream>>>(off, partial, N_NODES);
  scan_partials_kernel<<<1, 256, 0, stream>>>(partial, off, SCAN_BLOCKS, N_NODES);
  scan_apply_kernel<<<SCAN_BLOCKS, 256, 0, stream>>>(partial, off, cursor, N_NODES);
  partition_kernel<<<(NWAVES + 256) / 256, 256, 0, stream>>>(off, waveStart);
  scatter_kernel<<<(N_EDGES + 255) / 256, 256, 0, stream>>>(edst, esrc, eattr, cursor, srcs, eaC,
                                                            N_EDGES);

  // conv1
  agg_z_kernel<<<GRID_AGG, 256, 0, stream>>>(hB, off, waveStart, srcs, eaC, We1, be1, eps1, bufZ);
  mlp_kernel<<<3125, 256, 0, stream>>>(bufZ, 1, Wt11, b11, Wt12, b12, 1, 1, hB);
  // conv2
  agg_z_kernel<<<GRID_AGG, 256, 0, stream>>>(hB, off, waveStart, srcs, eaC, We2, be2, eps2, bufZ);
  mlp_kernel<<<3125, 256, 0, stream>>>(bufZ, 1, Wt21, b21, Wt22, b22, 1, 0, d_out);
}

// Round 3
// 516.672 us; speedup vs baseline: 1.2641x; 1.2641x over previous
//
#include <hip/hip_runtime.h>
#include <stdint.h>

#define N_NODES 200000
#define N_EDGES 600000
#define SCAN_CHUNK 1024
#define SCAN_BLOCKS ((N_NODES + SCAN_CHUNK - 1) / SCAN_CHUNK)  // 196
#define GRID_AGG 4096
#define NWAVES (GRID_AGG * 4)  // 16384 waves, ~36.6 edges each

typedef __attribute__((ext_vector_type(8))) short short8;
typedef __attribute__((ext_vector_type(4))) float floatx4;

static __device__ __forceinline__ unsigned short f2bf(float f) {
  union { float f; unsigned u; } c; c.f = f;
  unsigned u = c.u;
  unsigned r = (u + 0x7fffu + ((u >> 16) & 1u)) >> 16;
  return (unsigned short)r;
}
static __device__ __forceinline__ float asf(unsigned u) {
  union { unsigned u; float f; } c; c.u = u; return c.f;
}

// ---------------- weight prep: f32 [128][128] -> bf16 transposed [n][k] ----------------
__global__ __launch_bounds__(256) void prep_kernel(
    const float* w0, const float* w1, const float* w2, const float* w3, const float* w4,
    unsigned short* out) {
  const float* src;
  switch (blockIdx.y) {
    case 0: src = w0; break;
    case 1: src = w1; break;
    case 2: src = w2; break;
    case 3: src = w3; break;
    default: src = w4; break;
  }
  unsigned short* dst = out + (size_t)blockIdx.y * 16384;
  int t = blockIdx.x * 256 + threadIdx.x;  // 0..4095
#pragma unroll
  for (int i = 0; i < 4; ++i) {
    int idx = t + 4096 * i;  // idx = n*128 + k
    int n = idx >> 7, k = idx & 127;
    dst[idx] = f2bf(src[k * 128 + n]);
  }
}

// ---------------- CSR build ----------------
__global__ __launch_bounds__(256) void hist_kernel(const int* __restrict__ dst, int* deg, int E) {
  int e = blockIdx.x * 256 + threadIdx.x;
  if (e < E) atomicAdd(&deg[dst[e]], 1);
}

// pass 1: per-block partial sums of deg
__global__ __launch_bounds__(256) void scan_sum_kernel(const int* __restrict__ deg, int* partial,
                                                       int n) {
  __shared__ int wsum[4];
  const int tid = threadIdx.x, lane = tid & 63, wid = tid >> 6;
  int idx0 = blockIdx.x * SCAN_CHUNK + tid * 4;
  int s = 0;
#pragma unroll
  for (int j = 0; j < 4; ++j) {
    int ix = idx0 + j;
    if (ix < n) s += deg[ix];
  }
#pragma unroll
  for (int d = 32; d >= 1; d >>= 1) s += __shfl_down(s, d, 64);
  if (lane == 0) wsum[wid] = s;
  __syncthreads();
  if (tid == 0) partial[blockIdx.x] = wsum[0] + wsum[1] + wsum[2] + wsum[3];
}

// pass 2: single-block exclusive scan of partials (nb <= 256), writes off[n]=total
__global__ __launch_bounds__(256) void scan_partials_kernel(int* partial, int* off, int nb, int n) {
  __shared__ int wsum[4];
  const int tid = threadIdx.x, lane = tid & 63, wid = tid >> 6;
  int val = (tid < nb) ? partial[tid] : 0;
  int incl = val;
#pragma unroll
  for (int d = 1; d < 64; d <<= 1) {
    int t = __shfl_up(incl, d, 64);
    if (lane >= d) incl += t;
  }
  if (lane == 63) wsum[wid] = incl;
  __syncthreads();
  int base = 0;
  for (int w = 0; w < wid; ++w) base += wsum[w];
  int excl = base + incl - val;
  if (tid < nb) partial[tid] = excl;
  if (tid == 0) off[n] = wsum[0] + wsum[1] + wsum[2] + wsum[3];
}

// pass 3: per-block local exclusive scan + block base; writes off[] and cursor[]
__global__ __launch_bounds__(256) void scan_apply_kernel(const int* __restrict__ partial, int* off,
                                                         int* cursor, int n) {
  __shared__ int wsum[4];
  const int tid = threadIdx.x, lane = tid & 63, wid = tid >> 6;
  int idx0 = blockIdx.x * SCAN_CHUNK + tid * 4;
  int v[4];
  int s = 0;
#pragma unroll
  for (int j = 0; j < 4; ++j) {
    int ix = idx0 + j;
    v[j] = (ix < n) ? off[ix] : 0;
    s += v[j];
  }
  int incl = s;
#pragma unroll
  for (int d = 1; d < 64; d <<= 1) {
    int t = __shfl_up(incl, d, 64);
    if (lane >= d) incl += t;
  }
  if (lane == 63) wsum[wid] = incl;
  __syncthreads();
  int base = partial[blockIdx.x];
  for (int w = 0; w < wid; ++w) base += wsum[w];
  int running = base + incl - s;
#pragma unroll
  for (int j = 0; j < 4; ++j) {
    int ix = idx0 + j;
    if (ix < n) { off[ix] = running; cursor[ix] = running; }
    running += v[j];
  }
}

// scatter src node ids AND edge_attr rows into CSR (dst-sorted) order
__global__ __launch_bounds__(256) void scatter_kernel(const int* __restrict__ dst,
                                                      const int* __restrict__ src,
                                                      const float* __restrict__ eattr, int* cursor,
                                                      int* srcs, float* eaC, int E) {
  int e = blockIdx.x * 256 + threadIdx.x;
  if (e < E) {
    int p = atomicAdd(&cursor[dst[e]], 1);
    srcs[p] = src[e];
    const float4* q = (const float4*)(eattr + (size_t)e * 16);
    float4* o = (float4*)(eaC + (size_t)p * 16);
    o[0] = q[0]; o[1] = q[1]; o[2] = q[2]; o[3] = q[3];
  }
}

// wave w handles nodes [waveStart[w], waveStart[w+1]): balanced-by-edges contiguous ranges
__global__ __launch_bounds__(256) void partition_kernel(const int* __restrict__ off,
                                                        int* waveStart) {
  int w = blockIdx.x * 256 + threadIdx.x;
  if (w > NWAVES) return;
  if (w == NWAVES) { waveStart[w] = N_NODES; return; }
  long long t = (long long)w * N_EDGES / NWAVES;
  int lo = 0, hi = N_NODES;
  while (lo < hi) {
    int mid = (lo + hi) >> 1;
    if (off[mid] < (int)t) lo = mid + 1; else hi = mid;
  }
  waveStart[w] = lo;
}

// ---------------- aggregation + z = (1+eps)*h + sum relu(h[src]+ef) ----------------
// one wave per balanced node-range; lane covers channels (2*lane, 2*lane+1).
// v4 = v0 structure (per-node edge loop, batch of 4 -- measured 69us) + ONLY the
// scalar weight pin from v3 (VGPR 32->48, FETCH -18MB confirmed the remat was real).
// v3's flat pipeline regressed (144us): the data-dependent flush inside the
// unrolled compute loop killed unrolling -> serial branch chain. Keep v0 schedule.
__global__ __launch_bounds__(256) void agg_z_kernel(
    const unsigned short* __restrict__ hB, const int* __restrict__ off,
    const int* __restrict__ waveStart, const int* __restrict__ srcs,
    const float* __restrict__ eaC,
    const float* __restrict__ We, const float* __restrict__ be,
    const float* __restrict__ epsPtr, unsigned short* __restrict__ z) {
  const int lane = threadIdx.x & 63;
  const int wv = threadIdx.x >> 6;
  const int c = lane * 2;
  // wx[d] = We[d][c], wy[d] = We[d][c+1], pinned in VGPRs (prevent per-edge remat)
  float wx[16], wy[16];
#pragma unroll
  for (int d = 0; d < 16; ++d) {
    float2 t = *((const float2*)(We + d * 128 + c));
    wx[d] = t.x; wy[d] = t.y;
  }
#pragma unroll
  for (int d = 0; d < 16; ++d) {
    asm volatile("" : "+v"(wx[d]));
    asm volatile("" : "+v"(wy[d]));
  }
  const float2 bev = *((const float2*)(be + c));
  const float epsp = 1.0f + epsPtr[0];
  const int w = blockIdx.x * 4 + wv;
  const int n0 = waveStart[w];
  const int n1 = waveStart[w + 1];
  if (n0 >= n1) return;

  int obase = n0;
  int ix0 = obase + lane; if (ix0 > n1) ix0 = n1;
  int offv = off[ix0];
  int ii = __builtin_amdgcn_readlane(offv, 0);
  int ebase = ii;
  int sx0 = ebase + lane; if (sx0 > N_EDGES - 1) sx0 = N_EDGES - 1;
  int sbuf = srcs[sx0];

#define EDGE_COMPUTE(EIDX, HW) { \
    const float* ea = eaC + (size_t)(EIDX) * 16; \
    const float4 q0 = *((const float4*)(ea)); \
    const float4 q1 = *((const float4*)(ea + 4)); \
    const float4 q2 = *((const float4*)(ea + 8)); \
    const float4 q3 = *((const float4*)(ea + 12)); \
    float ax = bev.x, bx = 0.0f, ay = bev.y, by = 0.0f; \
    ax = fmaf(q0.x, wx[0], ax); ay = fmaf(q0.x, wy[0], ay); \
    bx = fmaf(q0.y, wx[1], bx); by = fmaf(q0.y, wy[1], by); \
    ax = fmaf(q0.z, wx[2], ax); ay = fmaf(q0.z, wy[2], ay); \
    bx = fmaf(q0.w, wx[3], bx); by = fmaf(q0.w, wy[3], by); \
    ax = fmaf(q1.x, wx[4], ax); ay = fmaf(q1.x, wy[4], ay); \
    bx = fmaf(q1.y, wx[5], bx); by = fmaf(q1.y, wy[5], by); \
    ax = fmaf(q1.z, wx[6], ax); ay = fmaf(q1.z, wy[6], ay); \
    bx = fmaf(q1.w, wx[7], bx); by = fmaf(q1.w, wy[7], by); \
    ax = fmaf(q2.x, wx[8], ax); ay = fmaf(q2.x, wy[8], ay); \
    bx = fmaf(q2.y, wx[9], bx); by = fmaf(q2.y, wy[9], by); \
    ax = fmaf(q2.z, wx[10], ax); ay = fmaf(q2.z, wy[10], ay); \
    bx = fmaf(q2.w, wx[11], bx); by = fmaf(q2.w, wy[11], by); \
    ax = fmaf(q3.x, wx[12], ax); ay = fmaf(q3.x, wy[12], ay); \
    bx = fmaf(q3.y, wx[13], bx); by = fmaf(q3.y, wy[13], by); \
    ax = fmaf(q3.z, wx[14], ax); ay = fmaf(q3.z, wy[14], ay); \
    bx = fmaf(q3.w, wx[15], bx); by = fmaf(q3.w, wy[15], by); \
    float mx = (ax + bx) + asf((HW) << 16); \
    float my = (ay + by) + asf((HW) & 0xffff0000u); \
    accx += fmaxf(mx, 0.0f); \
    accy += fmaxf(my, 0.0f); }

  for (int n = n0; n < n1; ++n) {
    if (n + 1 - obase >= 64) {
      obase = n;
      int ix = obase + lane; if (ix > n1) ix = n1;
      offv = off[ix];
    }
    const int eE = __builtin_amdgcn_readlane(offv, n + 1 - obase);
    const unsigned hwn = *((const unsigned*)(hB + (size_t)n * 128 + c));
    float accx = 0.0f, accy = 0.0f;
    while (ii < eE) {
      int m = eE - ii; if (m > 4) m = 4;
      if (ii + m > ebase + 64) {
        ebase = ii;
        int sx = ebase + lane; if (sx > N_EDGES - 1) sx = N_EDGES - 1;
        sbuf = srcs[sx];
      }
      const int j = ii - ebase;
      const int sn0 = __builtin_amdgcn_readlane(sbuf, j);
      const int sn1_ = __builtin_amdgcn_readlane(sbuf, (j + 1) & 63);
      const int sn2_ = __builtin_amdgcn_readlane(sbuf, (j + 2) & 63);
      const int sn3_ = __builtin_amdgcn_readlane(sbuf, (j + 3) & 63);
      unsigned hw0, hw1 = 0, hw2 = 0, hw3 = 0;
      hw0 = *((const unsigned*)(hB + (size_t)sn0 * 128 + c));
      if (m > 1) hw1 = *((const unsigned*)(hB + (size_t)sn1_ * 128 + c));
      if (m > 2) hw2 = *((const unsigned*)(hB + (size_t)sn2_ * 128 + c));
      if (m > 3) hw3 = *((const unsigned*)(hB + (size_t)sn3_ * 128 + c));
      EDGE_COMPUTE(ii, hw0);
      if (m > 1) EDGE_COMPUTE(ii + 1, hw1);
      if (m > 2) EDGE_COMPUTE(ii + 2, hw2);
      if (m > 3) EDGE_COMPUTE(ii + 3, hw3);
      ii += m;
    }
    const float hx = asf(hwn << 16);
    const float hy = asf(hwn & 0xffff0000u);
    unsigned p = (unsigned)f2bf(fmaf(epsp, hx, accx)) |
                 ((unsigned)f2bf(fmaf(epsp, hy, accy)) << 16);
    *((unsigned*)(z + (size_t)n * 128 + c)) = p;
  }
#undef EDGE_COMPUTE
}

// ---------------- fused (1 or 2)-layer MLP GEMM, M-tile=64, N=K=128, bf16 MFMA ----------------
__global__ __launch_bounds__(256) void mlp_kernel(
    const void* __restrict__ Ain, int aIsBf16,
    const unsigned short* __restrict__ W1t, const float* __restrict__ b1,
    const unsigned short* __restrict__ W2t, const float* __restrict__ b2,
    int twoStage, int outBf16, void* __restrict__ out) {
  __shared__ unsigned short sA[64][136];
  __shared__ unsigned short sW[128][136];
  const int tid = threadIdx.x;
  const int lane = tid & 63;
  const int wv = tid >> 6;
  const int lr = lane & 15, quad = lane >> 4;
  const int mw = wv >> 1, nw = wv & 1;
  const size_t rowBase = (size_t)blockIdx.x * 64;

  if (aIsBf16) {
    const uint4* src = (const uint4*)((const unsigned short*)Ain + rowBase * 128);
#pragma unroll
    for (int i = 0; i < 4; ++i) {
      int idx = tid + 256 * i;  // 0..1023 chunks of 8 bf16
      int r = idx >> 4, c8 = idx & 15;
      uint4 v = src[idx];
      *((uint4*)&sA[r][c8 * 8]) = v;
    }
  } else {
    const float4* src = (const float4*)((const float*)Ain + rowBase * 128);
#pragma unroll
    for (int i = 0; i < 8; ++i) {
      int idx = tid + 256 * i;  // 0..2047 float4
      int r = idx >> 5, c4 = idx & 31;
      float4 v = src[idx];
      uint2 p;
      p.x = (unsigned)f2bf(v.x) | ((unsigned)f2bf(v.y) << 16);
      p.y = (unsigned)f2bf(v.z) | ((unsigned)f2bf(v.w) << 16);
      *((uint2*)&sA[r][c4 * 4]) = p;
    }
  }
  {
    const uint4* srcw = (const uint4*)W1t;
#pragma unroll
    for (int i = 0; i < 8; ++i) {
      int idx = tid + 256 * i;  // 0..2047 chunks of 8 bf16
      int r = idx >> 4, c8 = idx & 15;
      *((uint4*)&sW[r][c8 * 8]) = srcw[idx];
    }
  }
  __syncthreads();

  floatx4 acc[2][4];
#pragma unroll
  for (int mi = 0; mi < 2; ++mi)
#pragma unroll
    for (int ni = 0; ni < 4; ++ni)
#pragma unroll
      for (int i = 0; i < 4; ++i) acc[mi][ni][i] = 0.0f;

#pragma unroll
  for (int kk = 0; kk < 4; ++kk) {
    short8 a[2], b[4];
#pragma unroll
    for (int mi = 0; mi < 2; ++mi)
      a[mi] = *((const short8*)&sA[32 * mw + 16 * mi + lr][kk * 32 + quad * 8]);
#pragma unroll
    for (int ni = 0; ni < 4; ++ni)
      b[ni] = *((const short8*)&sW[64 * nw + 16 * ni + lr][kk * 32 + quad * 8]);
#pragma unroll
    for (int mi = 0; mi < 2; ++mi)
#pragma unroll
      for (int ni = 0; ni < 4; ++ni)
        acc[mi][ni] = __builtin_amdgcn_mfma_f32_16x16x32_bf16(a[mi], b[ni], acc[mi][ni], 0, 0, 0);
  }

  if (!twoStage) {
#pragma unroll
    for (int mi = 0; mi < 2; ++mi)
#pragma unroll
      for (int ni = 0; ni < 4; ++ni)
#pragma unroll
        for (int i = 0; i < 4; ++i) {
          int row = 32 * mw + 16 * mi + quad * 4 + i;
          int col = 64 * nw + 16 * ni + lr;
          float v = fmaxf(acc[mi][ni][i] + b1[col], 0.0f);
          if (outBf16)
            ((unsigned short*)out)[(rowBase + row) * 128 + col] = f2bf(v);
          else
            ((float*)out)[(rowBase + row) * 128 + col] = v;
        }
    return;
  }

  __syncthreads();  // all stage-1 LDS reads done
  // write t = relu(z@W1+b1) into sA as bf16
#pragma unroll
  for (int mi = 0; mi < 2; ++mi)
#pragma unroll
    for (int ni = 0; ni < 4; ++ni)
#pragma unroll
      for (int i = 0; i < 4; ++i) {
        int row = 32 * mw + 16 * mi + quad * 4 + i;
        int col = 64 * nw + 16 * ni + lr;
        sA[row][col] = f2bf(fmaxf(acc[mi][ni][i] + b1[col], 0.0f));
      }
  // reload W2t
  {
    const uint4* srcw = (const uint4*)W2t;
#pragma unroll
    for (int i = 0; i < 8; ++i) {
      int idx = tid + 256 * i;
      int r = idx >> 4, c8 = idx & 15;
      *((uint4*)&sW[r][c8 * 8]) = srcw[idx];
    }
  }
  __syncthreads();

  floatx4 acc2[2][4];
#pragma unroll
  for (int mi = 0; mi < 2; ++mi)
#pragma unroll
    for (int ni = 0; ni < 4; ++ni)
#pragma unroll
      for (int i = 0; i < 4; ++i) acc2[mi][ni][i] = 0.0f;

#pragma unroll
  for (int kk = 0; kk < 4; ++kk) {
    short8 a[2], b[4];
#pragma unroll
    for (int mi = 0; mi < 2; ++mi)
      a[mi] = *((const short8*)&sA[32 * mw + 16 * mi + lr][kk * 32 + quad * 8]);
#pragma unroll
    for (int ni = 0; ni < 4; ++ni)
      b[ni] = *((const short8*)&sW[64 * nw + 16 * ni + lr][kk * 32 + quad * 8]);
#pragma unroll
    for (int mi = 0; mi < 2; ++mi)
#pragma unroll
      for (int ni = 0; ni < 4; ++ni)
        acc2[mi][ni] = __builtin_amdgcn_mfma_f32_16x16x32_bf16(a[mi], b[ni], acc2[mi][ni], 0, 0, 0);
  }

#pragma unroll
  for (int mi = 0; mi < 2; ++mi)
#pragma unroll
    for (int ni = 0; ni < 4; ++ni)
#pragma unroll
      for (int i = 0; i < 4; ++i) {
        int row = 32 * mw + 16 * mi + quad * 4 + i;
        int col = 64 * nw + 16 * ni + lr;
        float v = fmaxf(acc2[mi][ni][i] + b2[col], 0.0f);
        if (outBf16)
          ((unsigned short*)out)[(rowBase + row) * 128 + col] = f2bf(v);
        else
          ((float*)out)[(rowBase + row) * 128 + col] = v;
      }
}

extern "C" void kernel_launch(void* const* d_in, const int* in_sizes, int n_in,
                              void* d_out, int out_size, void* d_ws, size_t ws_size,
                              hipStream_t stream) {
  (void)in_sizes; (void)n_in; (void)out_size; (void)ws_size;
  const float* x = (const float*)d_in[0];
  const int* eidx = (const int*)d_in[1];
  const int* esrc = eidx;
  const int* edst = eidx + N_EDGES;
  const float* eattr = (const float*)d_in[2];
  const float* W_enc = (const float*)d_in[3];
  const float* b_enc = (const float*)d_in[4];
  const float* We1 = (const float*)d_in[5];
  const float* be1 = (const float*)d_in[6];
  const float* W11 = (const float*)d_in[7];
  const float* b11 = (const float*)d_in[8];
  const float* W12 = (const float*)d_in[9];
  const float* b12 = (const float*)d_in[10];
  const float* eps1 = (const float*)d_in[11];
  const float* We2 = (const float*)d_in[12];
  const float* be2 = (const float*)d_in[13];
  const float* W21 = (const float*)d_in[14];
  const float* b21 = (const float*)d_in[15];
  const float* W22 = (const float*)d_in[16];
  const float* b22 = (const float*)d_in[17];
  const float* eps2 = (const float*)d_in[18];

  char* ws = (char*)d_ws;
  size_t o = 0;
  unsigned short* wt = (unsigned short*)(ws + o); o += 163840;
  unsigned short* hB = (unsigned short*)(ws + o); o += 51200000ull;
  unsigned short* bufZ = (unsigned short*)(ws + o); o += 51200000ull;
  float* eaC = (float*)(ws + o); o += 38400000ull;
  int* off = (int*)(ws + o); o += ((N_NODES + 1) * 4 + 15) / 16 * 16;
  int* cursor = (int*)(ws + o); o += ((size_t)N_NODES * 4 + 15) / 16 * 16;
  int* srcs = (int*)(ws + o); o += (size_t)N_EDGES * 4;
  int* partial = (int*)(ws + o); o += (SCAN_BLOCKS * 4 + 15) / 16 * 16;
  int* waveStart = (int*)(ws + o); o += (size_t)(NWAVES + 1) * 4;

  unsigned short* Wt_enc = wt;
  unsigned short* Wt11 = wt + 16384;
  unsigned short* Wt12 = wt + 2 * 16384;
  unsigned short* Wt21 = wt + 3 * 16384;
  unsigned short* Wt22 = wt + 4 * 16384;

  hipMemsetAsync(off, 0, (N_NODES + 1) * sizeof(int), stream);
  prep_kernel<<<dim3(16, 5), 256, 0, stream>>>(W_enc, W11, W12, W21, W22, wt);

  // h0 = relu(x @ W_enc + b_enc) -> bf16
  mlp_kernel<<<3125, 256, 0, stream>>>(x, 0, Wt_enc, b_enc, Wt_enc, b_enc, 0, 1, hB);

  hist_kernel<<<(N_EDGES + 255) / 256, 256, 0, stream>>>(edst, off, N_EDGES);
  scan_sum_kernel<<<SCAN_BLOCKS, 256, 0, stream>>>(off, partial, N_NODES);
  scan_partials_kernel<<<1, 256, 0, stream>>>(partial, off, SCAN_BLOCKS, N_NODES);
  scan_apply_kernel<<<SCAN_BLOCKS, 256, 0, stream>>>(partial, off, cursor, N_NODES);
  partition_kernel<<<(NWAVES + 256) / 256, 256, 0, stream>>>(off, waveStart);
  scatter_kernel<<<(N_EDGES + 255) / 256, 256, 0, stream>>>(edst, esrc, eattr, cursor, srcs, eaC,
                                                            N_EDGES);

  // conv1
  agg_z_kernel<<<GRID_AGG, 256, 0, stream>>>(hB, off, waveStart, srcs, eaC, We1, be1, eps1, bufZ);
  mlp_kernel<<<3125, 256, 0, stream>>>(bufZ, 1, Wt11, b11, Wt12, b12, 1, 1, hB);
  // conv2
  agg_z_kernel<<<GRID_AGG, 256, 0, stream>>>(hB, off, waveStart, srcs, eaC, We2, be2, eps2, bufZ);
  mlp_kernel<<<3125, 256, 0, stream>>>(bufZ, 1, Wt21, b21, Wt22, b22, 1, 0, d_out);
}